// Round 10
// baseline (10594.978 us; speedup 1.0000x reference)
//
#include <hip/hip_runtime.h>
#include <math.h>

#define B 128
#define LATENT 512
#define H 1024

typedef unsigned short ushort_t;
typedef unsigned int uint_t;
typedef __bf16 bf16x8 __attribute__((ext_vector_type(8)));
typedef float f32x4 __attribute__((ext_vector_type(4)));

// ---------------- common small kernels ----------------

__global__ __launch_bounds__(256) void zero4_kernel(float4* __restrict__ p, int n4) {
  int i = blockIdx.x * blockDim.x + threadIdx.x;
  int stride = gridDim.x * blockDim.x;
  float4 z = {0.f, 0.f, 0.f, 0.f};
  for (; i < n4; i += stride) p[i] = z;
}

__device__ __forceinline__ void split_bf16(float f, ushort_t& h, ushort_t& l) {
  uint_t u = __float_as_uint(f);
  uint_t hb = (u + 0x7FFFu + ((u >> 16) & 1u)) >> 16;
  float fh = __uint_as_float(hb << 16);
  float r = f - fh;
  uint_t v = __float_as_uint(r);
  uint_t lb = (v + 0x7FFFu + ((v >> 16) & 1u)) >> 16;
  h = (ushort_t)hb; l = (ushort_t)lb;
}

__global__ __launch_bounds__(256) void split_kernel(const float* __restrict__ src,
                                                    ushort_t* __restrict__ hi,
                                                    ushort_t* __restrict__ lo, int n) {
  int i = blockIdx.x * blockDim.x + threadIdx.x;
  int stride = gridDim.x * blockDim.x;
  for (; i < n; i += stride) {
    ushort_t h, l;
    split_bf16(src[i], h, l);
    hi[i] = h; lo[i] = l;
  }
}

__device__ __forceinline__ float sigmoidf_(float v) { return 1.0f / (1.0f + expf(-v)); }

// ---------------- hierarchical grid barrier (round-6 form, known good) ----------------
__device__ __forceinline__ void grid_barrier(unsigned* bar, int tid, int bid) {
  __syncthreads();
  if (tid == 0) {
    const int g = bid & 7;
    unsigned* arr    = bar + (g << 6);
    unsigned* rel    = bar + 1024 + (g << 6);
    unsigned* master = bar + 2048;
    unsigned gen = __hip_atomic_load(rel, __ATOMIC_RELAXED, __HIP_MEMORY_SCOPE_AGENT);
    unsigned a = __hip_atomic_fetch_add(arr, 1u, __ATOMIC_ACQ_REL, __HIP_MEMORY_SCOPE_AGENT);
    if (a == 31u) {
      __hip_atomic_store(arr, 0u, __ATOMIC_RELAXED, __HIP_MEMORY_SCOPE_AGENT);
      unsigned m = __hip_atomic_fetch_add(master, 1u, __ATOMIC_ACQ_REL, __HIP_MEMORY_SCOPE_AGENT);
      if (m == 7u) {
        __hip_atomic_store(master, 0u, __ATOMIC_RELAXED, __HIP_MEMORY_SCOPE_AGENT);
        #pragma unroll
        for (int i = 0; i < 8; ++i)
          __hip_atomic_fetch_add(bar + 1024 + (i << 6), 1u, __ATOMIC_ACQ_REL, __HIP_MEMORY_SCOPE_AGENT);
      }
    }
    while (__hip_atomic_load(rel, __ATOMIC_RELAXED, __HIP_MEMORY_SCOPE_AGENT) == gen)
      __builtin_amdgcn_s_sleep(1);
    (void)__hip_atomic_load(rel, __ATOMIC_ACQUIRE, __HIP_MEMORY_SCOPE_AGENT);
  }
  __syncthreads();
}

// ---------------- one GEMM phase: REGISTER-STREAMED, no LDS in K-loop ----------------
// Block tile 32b x 16j (xNG gates); 4 waves k-split each 128-wide window.
// Each lane loads its own MFMA fragments (A: 4 x bf16x8, W: 2*NG x bf16x8) via
// plain global loads -> compiler pipelines with fine-grained vmcnt, ZERO barriers
// in the K-loop. LDS used only for the cross-wave reduce.
// MFMA order identical to rounds 2-9 -> bitwise-identical accumulation.
template <int NG, int PH, int EPI, int K1, int K2>
__device__ __forceinline__ void phase_mm(
    char* smem, const int tid, const int bid, const int jb8, const bool active,
    const ushort_t* aAh, const ushort_t* aAl, int aApitch,
    const ushort_t* wAh, const ushort_t* wAl,
    const ushort_t* aBh, const ushort_t* aBl, int aBpitch,
    const ushort_t* wBh, const ushort_t* wBl,
    const float* bih, const float* bhh,
    const float* h_prev, float* h_out,
    ushort_t* out_hi, ushort_t* out_lo, int split_pitch,
    const float* bias, float* out_f32, int out_pitch)
{
  if (!active) return;
  constexpr int PGc = PH * NG;
  constexpr int NW1 = K1 >> 7;
  constexpr int NW2 = K2 >> 7;

  const int xcd = bid & 7;
  const int wi = bid >> 3;
  const int Mb = wi & 3;
  const int jb = xcd * jb8 + (wi >> 2);
  const int b0 = Mb * 32;
  const int j0 = jb * 16;

  const int s  = tid >> 6;       // wave = k-slice owner
  const int l6 = tid & 63;
  const int r  = l6 & 15;        // fragment row
  const int ksub = s * 32 + (l6 >> 4) * 8;  // elem offset within a 128-window

  f32x4 accA[NG][2];
  f32x4 accB[NG][2];
  #pragma unroll
  for (int gg = 0; gg < NG; ++gg)
    #pragma unroll
    for (int mf = 0; mf < 2; ++mf) {
      accA[gg][mf] = (f32x4){0.f, 0.f, 0.f, 0.f};
      accB[gg][mf] = (f32x4){0.f, 0.f, 0.f, 0.f};
    }

  auto seg = [&](int nw, const ushort_t* ah, const ushort_t* al, int apitch,
                 const ushort_t* wh, const ushort_t* wl, int K,
                 f32x4 (&acc)[NG][2]) {
    const ushort_t* pah0 = ah + (size_t)(b0 + r) * apitch + ksub;
    const ushort_t* pah1 = ah + (size_t)(b0 + 16 + r) * apitch + ksub;
    const ushort_t* pal0 = al + (size_t)(b0 + r) * apitch + ksub;
    const ushort_t* pal1 = al + (size_t)(b0 + 16 + r) * apitch + ksub;
    const ushort_t* pwh[NG];
    const ushort_t* pwl[NG];
    #pragma unroll
    for (int gg = 0; gg < NG; ++gg) {
      const int wrow = (NG == 3) ? (gg * H + j0 + r) : (j0 + r);
      pwh[gg] = wh + (size_t)wrow * K + ksub;
      pwl[gg] = wl + (size_t)wrow * K + ksub;
    }
    #pragma unroll 4
    for (int w = 0; w < nw; ++w) {
      const int o = w << 7;
      bf16x8 ah0 = *(const bf16x8*)(const void*)(pah0 + o);
      bf16x8 ah1 = *(const bf16x8*)(const void*)(pah1 + o);
      bf16x8 al0 = *(const bf16x8*)(const void*)(pal0 + o);
      bf16x8 al1 = *(const bf16x8*)(const void*)(pal1 + o);
      #pragma unroll
      for (int gg = 0; gg < NG; ++gg) {
        bf16x8 whv = *(const bf16x8*)(const void*)(pwh[gg] + o);
        bf16x8 wlv = *(const bf16x8*)(const void*)(pwl[gg] + o);
        acc[gg][0] = __builtin_amdgcn_mfma_f32_16x16x32_bf16(ah0, whv, acc[gg][0], 0, 0, 0);
        acc[gg][0] = __builtin_amdgcn_mfma_f32_16x16x32_bf16(ah0, wlv, acc[gg][0], 0, 0, 0);
        acc[gg][0] = __builtin_amdgcn_mfma_f32_16x16x32_bf16(al0, whv, acc[gg][0], 0, 0, 0);
        acc[gg][1] = __builtin_amdgcn_mfma_f32_16x16x32_bf16(ah1, whv, acc[gg][1], 0, 0, 0);
        acc[gg][1] = __builtin_amdgcn_mfma_f32_16x16x32_bf16(ah1, wlv, acc[gg][1], 0, 0, 0);
        acc[gg][1] = __builtin_amdgcn_mfma_f32_16x16x32_bf16(al1, whv, acc[gg][1], 0, 0, 0);
      }
    }
  };

  seg(NW1, aAh, aAl, aApitch, wAh, wAl, K1, accA);
  if constexpr (PH == 2)
    seg(NW2, aBh, aBl, aBpitch, wBh, wBl, K2, accB);

  // ---- cross-wave reduce (LDS, as in rounds 2-9) ----
  __syncthreads();   // protect reduce-LDS reuse from previous phase's epilogue
  const int lane = tid & 63;
  #pragma unroll
  for (int gg = 0; gg < NG; ++gg)
    #pragma unroll
    for (int mf = 0; mf < 2; ++mf) {
      *(f32x4*)(smem + (((s * PGc + gg) * 2 + mf) * 64 + lane) * 16) = accA[gg][mf];
      if (PH == 2)
        *(f32x4*)(smem + (((s * PGc + NG + gg) * 2 + mf) * 64 + lane) * 16) = accB[gg][mf];
    }
  __syncthreads();

  for (int o = tid; o < 512; o += 256) {
    int bb = o >> 4, jj = o & 15;
    int mf = bb >> 4, br = bb & 15, qq = br >> 2, rg = br & 3;
    int ln = jj + qq * 16;
    float v[PGc];
    #pragma unroll
    for (int gp = 0; gp < PGc; ++gp) {
      float sum = 0.f;
      #pragma unroll
      for (int ss = 0; ss < 4; ++ss)
        sum += *(const float*)(smem + (((ss * PGc + gp) * 2 + mf) * 64 + ln) * 16 + rg * 4);
      v[gp] = sum;
    }
    int bglob = b0 + bb, jglob = j0 + jj;
    if (EPI == 0) {
      float ir = v[0] + bih[jglob];
      float iz = v[1] + bih[H + jglob];
      float in_ = v[2] + bih[2 * H + jglob];
      float hr = v[3] + bhh[jglob];
      float hz = v[4] + bhh[H + jglob];
      float hn = v[5] + bhh[2 * H + jglob];
      float rr_ = sigmoidf_(ir + hr);
      float zz_ = sigmoidf_(iz + hz);
      float nn_ = tanhf(in_ + rr_ * hn);
      float hp = h_prev[(size_t)bglob * H + jglob];
      float ho = (1.f - zz_) * nn_ + zz_ * hp;
      h_out[(size_t)bglob * H + jglob] = ho;
      ushort_t hb, lb;
      split_bf16(ho, hb, lb);
      out_hi[(size_t)bglob * H + jglob] = hb;
      out_lo[(size_t)bglob * H + jglob] = lb;
    } else if (EPI == 1) {
      float vv = v[0] + bias[jglob];
      vv = fmaxf(vv, 0.f);
      ushort_t hb, lb;
      split_bf16(vv, hb, lb);
      out_hi[(size_t)bglob * split_pitch + jglob] = hb;
      out_lo[(size_t)bglob * split_pitch + jglob] = lb;
    } else {
      float vv = v[0] + bias[jglob];
      out_f32[(size_t)bglob * out_pitch + jglob] = vv;
      ushort_t hb, lb;
      split_bf16(vv, hb, lb);
      out_hi[(size_t)bglob * split_pitch + jglob] = hb;
      out_lo[(size_t)bglob * split_pitch + jglob] = lb;
    }
  }
  __syncthreads();
}

// ---------------- persistent kernel ----------------

struct PParams {
  const ushort_t *ctxh, *ctxl;
  const ushort_t *wih0h, *wih0l, *whh0h, *whh0l;
  const ushort_t *wih1h, *wih1l, *whh1h, *whh1l;
  const ushort_t *w1h, *w1l, *w2h, *w2l;
  const float *bih0, *bhh0, *bih1, *bhh1, *bp1, *bp2;
  float *h0f0, *h0f1, *h1f0, *h1f1;
  ushort_t *h0hi0, *h0lo0, *h0hi1, *h0lo1;
  ushort_t *h1hi0, *h1lo0, *h1hi1, *h1lo1;
  ushort_t *h0Ahi, *h0Alo;      // all-t encoder h0 split [T_in][B][H]
  ushort_t *phi, *plo, *yhi, *ylo;
  float* out;
  unsigned* bar;
  int T_in, n_pred, ctx_pitch;
};

__global__ __launch_bounds__(256, 1) void gru_persistent(PParams P) {
  __shared__ char smem[49152];   // cross-wave reduce only (48KB max: PGc=6)
  const int tid = threadIdx.x;
  const int bid = blockIdx.x;

  float* h0f[2] = {P.h0f0, P.h0f1};
  float* h1f[2] = {P.h1f0, P.h1f1};
  ushort_t* h0hi[2] = {P.h0hi0, P.h0hi1};
  ushort_t* h0lo[2] = {P.h0lo0, P.h0lo1};
  ushort_t* h1hi[2] = {P.h1hi0, P.h1hi1};
  ushort_t* h1lo[2] = {P.h1lo0, P.h1lo1};

  int p0 = 0, p1 = 0;

  // -------- encoder chain 1: layer-0 for all t (W L2-resident) --------
  const ushort_t* e0ph = h0hi[0];
  const ushort_t* e0pl = h0lo[0];
  #pragma unroll 1
  for (int t = 0; t < P.T_in; ++t) {
    const int n0 = p0 ^ 1;
    ushort_t* oh = P.h0Ahi + (size_t)t * B * H;
    ushort_t* ol = P.h0Alo + (size_t)t * B * H;
    phase_mm<3, 2, 0, 512, 1024>(smem, tid, bid, 8, true,
        P.ctxh + (size_t)t * LATENT, P.ctxl + (size_t)t * LATENT, P.ctx_pitch,
        P.wih0h, P.wih0l,
        e0ph, e0pl, H, P.whh0h, P.whh0l,
        P.bih0, P.bhh0, h0f[p0], h0f[n0], oh, ol, H,
        nullptr, nullptr, 0);
    grid_barrier(P.bar, tid, bid);
    e0ph = oh; e0pl = ol; p0 = n0;
  }

  // -------- encoder chain 2: layer-1 for all t --------
  #pragma unroll 1
  for (int t = 0; t < P.T_in; ++t) {
    const int n1 = p1 ^ 1;
    phase_mm<3, 2, 0, 1024, 1024>(smem, tid, bid, 8, true,
        P.h0Ahi + (size_t)t * B * H, P.h0Alo + (size_t)t * B * H, H,
        P.wih1h, P.wih1l,
        h1hi[p1], h1lo[p1], H, P.whh1h, P.whh1l,
        P.bih1, P.bhh1, h1f[p1], h1f[n1], h1hi[n1], h1lo[n1], H,
        nullptr, nullptr, 0);
    grid_barrier(P.bar, tid, bid);
    p1 = n1;
  }

  // -------- decoder --------
  const ushort_t* d0ph = e0ph;
  const ushort_t* d0pl = e0pl;
  #pragma unroll 1
  for (int t = 0; t < P.n_pred; ++t) {
    const ushort_t *xh, *xl; int xpitch;
    if (t == 0) {
      xh = P.ctxh + (size_t)(P.T_in - 1) * LATENT;
      xl = P.ctxl + (size_t)(P.T_in - 1) * LATENT;
      xpitch = P.ctx_pitch;
    } else {
      xh = P.yhi; xl = P.ylo; xpitch = LATENT;
    }
    const int n0 = p0 ^ 1;
    phase_mm<3, 2, 0, 512, 1024>(smem, tid, bid, 8, true,
        xh, xl, xpitch,
        P.wih0h, P.wih0l,
        d0ph, d0pl, H, P.whh0h, P.whh0l,
        P.bih0, P.bhh0, h0f[p0], h0f[n0], h0hi[n0], h0lo[n0], H,
        nullptr, nullptr, 0);
    grid_barrier(P.bar, tid, bid);
    d0ph = h0hi[n0]; d0pl = h0lo[n0];
    const int n1 = p1 ^ 1;
    phase_mm<3, 2, 0, 1024, 1024>(smem, tid, bid, 8, true,
        h0hi[n0], h0lo[n0], H,
        P.wih1h, P.wih1l,
        h1hi[p1], h1lo[p1], H, P.whh1h, P.whh1l,
        P.bih1, P.bhh1, h1f[p1], h1f[n1], h1hi[n1], h1lo[n1], H,
        nullptr, nullptr, 0);
    grid_barrier(P.bar, tid, bid);
    // p = relu(h1 @ w1^T + bp1)
    phase_mm<1, 1, 1, 1024, 1024>(smem, tid, bid, 8, true,
        h1hi[n1], h1lo[n1], H,
        P.w1h, P.w1l,
        nullptr, nullptr, 0, nullptr, nullptr,
        nullptr, nullptr, nullptr, nullptr, P.phi, P.plo, H,
        P.bp1, nullptr, 0);
    grid_barrier(P.bar, tid, bid);
    // y = p @ w2^T + bp2 -> out[:, t, :] + y split (N=512 -> 128 active blocks)
    phase_mm<1, 1, 2, 1024, 1024>(smem, tid, bid, 4, bid < 128,
        P.phi, P.plo, H,
        P.w2h, P.w2l,
        nullptr, nullptr, 0, nullptr, nullptr,
        nullptr, nullptr, nullptr, nullptr, P.yhi, P.ylo, LATENT,
        P.bp2, P.out + (size_t)t * LATENT, P.n_pred * LATENT);
    grid_barrier(P.bar, tid, bid);
    p0 = n0; p1 = n1;
  }
}

// ---------------- fp32 fallback (round-1, known-good) ----------------

__global__ __launch_bounds__(256) void gru_cell_kernel(
    const float* __restrict__ x, int xs, int Kih,
    const float* __restrict__ h_prev,
    const float* __restrict__ wih, const float* __restrict__ whh,
    const float* __restrict__ bih, const float* __restrict__ bhh,
    float* __restrict__ h_out)
{
  __shared__ float Xs[32][33];
  __shared__ float Ws[48][33];
  const int tid = threadIdx.x;
  const int b0 = blockIdx.x * 32;
  const int j0 = blockIdx.y * 16;
  const int bg = tid & 15;
  const int jj = tid >> 4;
  const int j = j0 + jj;
  float accA[2][3];
  float accB[2][3];
  #pragma unroll
  for (int g = 0; g < 3; ++g) {
    const float bi = bih[g * H + j];
    const float bh = bhh[g * H + j];
    accA[0][g] = bi; accA[1][g] = bi;
    accB[0][g] = bh; accB[1][g] = bh;
  }
  for (int k0 = 0; k0 < Kih; k0 += 32) {
    {
      const int rr = tid >> 3, c4 = (tid & 7) << 2;
      const float4 v = *reinterpret_cast<const float4*>(&x[(size_t)(b0 + rr) * xs + k0 + c4]);
      Xs[rr][c4 + 0] = v.x; Xs[rr][c4 + 1] = v.y; Xs[rr][c4 + 2] = v.z; Xs[rr][c4 + 3] = v.w;
    }
    for (int li = tid; li < 48 * 8; li += 256) {
      const int rr = li >> 3, c4 = (li & 7) << 2;
      const int g = rr >> 4, jr = rr & 15;
      const float4 v = *reinterpret_cast<const float4*>(&wih[(size_t)(g * H + j0 + jr) * Kih + k0 + c4]);
      Ws[rr][c4 + 0] = v.x; Ws[rr][c4 + 1] = v.y; Ws[rr][c4 + 2] = v.z; Ws[rr][c4 + 3] = v.w;
    }
    __syncthreads();
    #pragma unroll
    for (int k = 0; k < 32; ++k) {
      const float x0 = Xs[bg][k];
      const float x1 = Xs[bg + 16][k];
      #pragma unroll
      for (int g = 0; g < 3; ++g) {
        const float wv = Ws[g * 16 + jj][k];
        accA[0][g] = fmaf(x0, wv, accA[0][g]);
        accA[1][g] = fmaf(x1, wv, accA[1][g]);
      }
    }
    __syncthreads();
  }
  for (int k0 = 0; k0 < H; k0 += 32) {
    {
      const int rr = tid >> 3, c4 = (tid & 7) << 2;
      const float4 v = *reinterpret_cast<const float4*>(&h_prev[(size_t)(b0 + rr) * H + k0 + c4]);
      Xs[rr][c4 + 0] = v.x; Xs[rr][c4 + 1] = v.y; Xs[rr][c4 + 2] = v.z; Xs[rr][c4 + 3] = v.w;
    }
    for (int li = tid; li < 48 * 8; li += 256) {
      const int rr = li >> 3, c4 = (li & 7) << 2;
      const int g = rr >> 4, jr = rr & 15;
      const float4 v = *reinterpret_cast<const float4*>(&whh[(size_t)(g * H + j0 + jr) * H + k0 + c4]);
      Ws[rr][c4 + 0] = v.x; Ws[rr][c4 + 1] = v.y; Ws[rr][c4 + 2] = v.z; Ws[rr][c4 + 3] = v.w;
    }
    __syncthreads();
    #pragma unroll
    for (int k = 0; k < 32; ++k) {
      const float h0v = Xs[bg][k];
      const float h1v = Xs[bg + 16][k];
      #pragma unroll
      for (int g = 0; g < 3; ++g) {
        const float wv = Ws[g * 16 + jj][k];
        accB[0][g] = fmaf(h0v, wv, accB[0][g]);
        accB[1][g] = fmaf(h1v, wv, accB[1][g]);
      }
    }
    __syncthreads();
  }
  #pragma unroll
  for (int i = 0; i < 2; ++i) {
    const int b = b0 + bg + i * 16;
    const float hp = h_prev[(size_t)b * H + j];
    const float r = sigmoidf_(accA[i][0] + accB[i][0]);
    const float z = sigmoidf_(accA[i][1] + accB[i][1]);
    const float n = tanhf(accA[i][2] + r * accB[i][2]);
    h_out[(size_t)b * H + j] = (1.0f - z) * n + z * hp;
  }
}

__global__ __launch_bounds__(256) void gemm_bias_kernel(
    const float* __restrict__ X, int xs, int K,
    const float* __restrict__ W, const float* __restrict__ bias,
    float* __restrict__ out1, int o1s,
    float* __restrict__ out2, int o2s,
    int relu)
{
  __shared__ float Xs[32][33];
  __shared__ float Ws[16][33];
  const int tid = threadIdx.x;
  const int b0 = blockIdx.x * 32;
  const int n0 = blockIdx.y * 16;
  const int bg = tid & 15;
  const int nn = tid >> 4;
  const int n = n0 + nn;
  float acc0 = bias[n];
  float acc1 = acc0;
  for (int k0 = 0; k0 < K; k0 += 32) {
    {
      const int rr = tid >> 3, c4 = (tid & 7) << 2;
      const float4 v = *reinterpret_cast<const float4*>(&X[(size_t)(b0 + rr) * xs + k0 + c4]);
      Xs[rr][c4 + 0] = v.x; Xs[rr][c4 + 1] = v.y; Xs[rr][c4 + 2] = v.z; Xs[rr][c4 + 3] = v.w;
    }
    if (tid < 128) {
      const int rr = tid >> 3, c4 = (tid & 7) << 2;
      const float4 v = *reinterpret_cast<const float4*>(&W[(size_t)(n0 + rr) * K + k0 + c4]);
      Ws[rr][c4 + 0] = v.x; Ws[rr][c4 + 1] = v.y; Ws[rr][c4 + 2] = v.z; Ws[rr][c4 + 3] = v.w;
    }
    __syncthreads();
    #pragma unroll
    for (int k = 0; k < 32; ++k) {
      const float wv = Ws[nn][k];
      acc0 = fmaf(Xs[bg][k], wv, acc0);
      acc1 = fmaf(Xs[bg + 16][k], wv, acc1);
    }
    __syncthreads();
  }
  if (relu) { acc0 = fmaxf(acc0, 0.0f); acc1 = fmaxf(acc1, 0.0f); }
  const int ba = b0 + bg, bb = b0 + bg + 16;
  out1[(size_t)ba * o1s + n] = acc0;
  out1[(size_t)bb * o1s + n] = acc1;
  if (out2 != nullptr) {
    out2[(size_t)ba * o2s + n] = acc0;
    out2[(size_t)bb * o2s + n] = acc1;
  }
}

// ---------------- host launch ----------------

extern "C" void kernel_launch(void* const* d_in, const int* in_sizes, int n_in,
                              void* d_out, int out_size, void* d_ws, size_t ws_size,
                              hipStream_t stream) {
  (void)n_in;
  const float* ctx  = (const float*)d_in[0];
  const float* wih0 = (const float*)d_in[1];
  const float* whh0 = (const float*)d_in[2];
  const float* bih0 = (const float*)d_in[3];
  const float* bhh0 = (const float*)d_in[4];
  const float* wih1 = (const float*)d_in[5];
  const float* whh1 = (const float*)d_in[6];
  const float* bih1 = (const float*)d_in[7];
  const float* bhh1 = (const float*)d_in[8];
  const float* w1   = (const float*)d_in[9];
  const float* bp1  = (const float*)d_in[10];
  const float* w2   = (const float*)d_in[11];
  const float* bp2  = (const float*)d_in[12];

  const int T_in   = in_sizes[0] / (B * LATENT);
  const int n_pred = out_size / (B * LATENT);
  float* out = (float*)d_out;

  // ---- ws layout for MFMA path ----
  size_t cur = 0;
  auto alloc = [&](size_t bytes) -> void* {
    void* p = (char*)d_ws + cur;
    cur += (bytes + 255) & ~(size_t)255;
    return p;
  };
  const int E_wih0 = 3 * H * LATENT, E_whh0 = 3 * H * H;
  const int E_wih1 = 3 * H * H, E_whh1 = 3 * H * H;
  const int E_w1 = H * H, E_w2 = LATENT * H;
  const int E_ctx = in_sizes[0];

  ushort_t* wih0h = (ushort_t*)alloc(E_wih0 * 2); ushort_t* wih0l = (ushort_t*)alloc(E_wih0 * 2);
  ushort_t* whh0h = (ushort_t*)alloc(E_whh0 * 2); ushort_t* whh0l = (ushort_t*)alloc(E_whh0 * 2);
  ushort_t* wih1h = (ushort_t*)alloc(E_wih1 * 2); ushort_t* wih1l = (ushort_t*)alloc(E_wih1 * 2);
  ushort_t* whh1h = (ushort_t*)alloc(E_whh1 * 2); ushort_t* whh1l = (ushort_t*)alloc(E_whh1 * 2);
  ushort_t* w1h   = (ushort_t*)alloc(E_w1 * 2);   ushort_t* w1l   = (ushort_t*)alloc(E_w1 * 2);
  ushort_t* w2h   = (ushort_t*)alloc(E_w2 * 2);   ushort_t* w2l   = (ushort_t*)alloc(E_w2 * 2);
  ushort_t* ctxh  = (ushort_t*)alloc((size_t)E_ctx * 2);
  ushort_t* ctxl  = (ushort_t*)alloc((size_t)E_ctx * 2);
  ushort_t* h0Ahi = (ushort_t*)alloc((size_t)T_in * B * H * 2);
  ushort_t* h0Alo = (ushort_t*)alloc((size_t)T_in * B * H * 2);
  size_t zero_start = cur;
  float* h0f[2]; float* h1f[2];
  ushort_t* h0hi[2]; ushort_t* h0lo[2]; ushort_t* h1hi[2]; ushort_t* h1lo[2];
  h0f[0] = (float*)alloc(B * H * 4); h0f[1] = (float*)alloc(B * H * 4);
  h1f[0] = (float*)alloc(B * H * 4); h1f[1] = (float*)alloc(B * H * 4);
  h0hi[0] = (ushort_t*)alloc(B * H * 2); h0lo[0] = (ushort_t*)alloc(B * H * 2);
  h0hi[1] = (ushort_t*)alloc(B * H * 2); h0lo[1] = (ushort_t*)alloc(B * H * 2);
  h1hi[0] = (ushort_t*)alloc(B * H * 2); h1lo[0] = (ushort_t*)alloc(B * H * 2);
  h1hi[1] = (ushort_t*)alloc(B * H * 2); h1lo[1] = (ushort_t*)alloc(B * H * 2);
  ushort_t* phi = (ushort_t*)alloc(B * H * 2); ushort_t* plo = (ushort_t*)alloc(B * H * 2);
  ushort_t* yhi = (ushort_t*)alloc(B * LATENT * 2); ushort_t* ylo = (ushort_t*)alloc(B * LATENT * 2);
  unsigned* bar = (unsigned*)alloc(16384);
  size_t zero_bytes = cur - zero_start;
  size_t required = cur;

  if (ws_size >= required) {
    // ---------- MFMA split-bf16 persistent path ----------
    auto splitN = [&](const float* s, ushort_t* hi, ushort_t* lo, int n) {
      int blocks = (n + 255) / 256; if (blocks > 2048) blocks = 2048;
      split_kernel<<<blocks, 256, 0, stream>>>(s, hi, lo, n);
    };
    splitN(wih0, wih0h, wih0l, E_wih0);
    splitN(whh0, whh0h, whh0l, E_whh0);
    splitN(wih1, wih1h, wih1l, E_wih1);
    splitN(whh1, whh1h, whh1l, E_whh1);
    splitN(w1, w1h, w1l, E_w1);
    splitN(w2, w2h, w2l, E_w2);
    splitN(ctx, ctxh, ctxl, E_ctx);
    {
      int n4 = (int)(zero_bytes / 16);
      zero4_kernel<<<2048, 256, 0, stream>>>((float4*)((char*)d_ws + zero_start), n4);
    }

    PParams P;
    P.ctxh = ctxh; P.ctxl = ctxl;
    P.wih0h = wih0h; P.wih0l = wih0l; P.whh0h = whh0h; P.whh0l = whh0l;
    P.wih1h = wih1h; P.wih1l = wih1l; P.whh1h = whh1h; P.whh1l = whh1l;
    P.w1h = w1h; P.w1l = w1l; P.w2h = w2h; P.w2l = w2l;
    P.bih0 = bih0; P.bhh0 = bhh0; P.bih1 = bih1; P.bhh1 = bhh1;
    P.bp1 = bp1; P.bp2 = bp2;
    P.h0f0 = h0f[0]; P.h0f1 = h0f[1]; P.h1f0 = h1f[0]; P.h1f1 = h1f[1];
    P.h0hi0 = h0hi[0]; P.h0lo0 = h0lo[0]; P.h0hi1 = h0hi[1]; P.h0lo1 = h0lo[1];
    P.h1hi0 = h1hi[0]; P.h1lo0 = h1lo[0]; P.h1hi1 = h1hi[1]; P.h1lo1 = h1lo[1];
    P.h0Ahi = h0Ahi; P.h0Alo = h0Alo;
    P.phi = phi; P.plo = plo; P.yhi = yhi; P.ylo = ylo;
    P.out = out; P.bar = bar;
    P.T_in = T_in; P.n_pred = n_pred; P.ctx_pitch = T_in * LATENT;

    gru_persistent<<<256, 256, 0, stream>>>(P);
    return;
  }

  // ---------- fp32 fallback path (round-1) ----------
  float* ws = (float*)d_ws;
  float* h0a = ws;
  float* h0b = h0a + (size_t)B * H;
  float* h1a = h0b + (size_t)B * H;
  float* h1b = h1a + (size_t)B * H;
  float* p   = h1b + (size_t)B * H;
  {
    int n4 = (4 * B * H) / 4;
    zero4_kernel<<<256, 256, 0, stream>>>((float4*)h0a, n4);
  }
  float* y = p + (size_t)B * H;
  float* h0p = h0a; float* h0n = h0b;
  float* h1p = h1a; float* h1n = h1b;
  const dim3 cgrid(4, 64);
  for (int t = 0; t < T_in; ++t) {
    const float* x = ctx + (size_t)t * LATENT;
    gru_cell_kernel<<<cgrid, 256, 0, stream>>>(x, T_in * LATENT, LATENT,
                                               h0p, wih0, whh0, bih0, bhh0, h0n);
    gru_cell_kernel<<<cgrid, 256, 0, stream>>>(h0n, H, H,
                                               h1p, wih1, whh1, bih1, bhh1, h1n);
    float* tmp;
    tmp = h0p; h0p = h0n; h0n = tmp;
    tmp = h1p; h1p = h1n; h1n = tmp;
  }
  for (int t = 0; t < n_pred; ++t) {
    const float* x; int xstride;
    if (t == 0) { x = ctx + (size_t)(T_in - 1) * LATENT; xstride = T_in * LATENT; }
    else        { x = y; xstride = LATENT; }
    gru_cell_kernel<<<cgrid, 256, 0, stream>>>(x, xstride, LATENT,
                                               h0p, wih0, whh0, bih0, bhh0, h0n);
    gru_cell_kernel<<<cgrid, 256, 0, stream>>>(h0n, H, H,
                                               h1p, wih1, whh1, bih1, bhh1, h1n);
    gemm_bias_kernel<<<dim3(4, H / 16), 256, 0, stream>>>(h1n, H, H, w1, bp1,
                                                          p, H, nullptr, 0, 1);
    gemm_bias_kernel<<<dim3(4, LATENT / 16), 256, 0, stream>>>(p, H, H, w2, bp2,
                                                               y, LATENT,
                                                               out + (size_t)t * LATENT,
                                                               n_pred * LATENT, 0);
    float* tmp;
    tmp = h0p; h0p = h0n; h0n = tmp;
    tmp = h1p; h1p = h1n; h1n = tmp;
  }
}

// Round 11
// 7984.129 us; speedup vs baseline: 1.3270x; 1.3270x over previous
//
#include <hip/hip_runtime.h>
#include <math.h>

#define B 128
#define LATENT 512
#define H 1024

typedef unsigned short ushort_t;
typedef unsigned int uint_t;
typedef __bf16 bf16x8 __attribute__((ext_vector_type(8)));
typedef float f32x4 __attribute__((ext_vector_type(4)));

// ---------------- common small kernels ----------------

__global__ __launch_bounds__(256) void zero4_kernel(float4* __restrict__ p, int n4) {
  int i = blockIdx.x * blockDim.x + threadIdx.x;
  int stride = gridDim.x * blockDim.x;
  float4 z = {0.f, 0.f, 0.f, 0.f};
  for (; i < n4; i += stride) p[i] = z;
}

__device__ __forceinline__ void split_bf16(float f, ushort_t& h, ushort_t& l) {
  uint_t u = __float_as_uint(f);
  uint_t hb = (u + 0x7FFFu + ((u >> 16) & 1u)) >> 16;
  float fh = __uint_as_float(hb << 16);
  float r = f - fh;
  uint_t v = __float_as_uint(r);
  uint_t lb = (v + 0x7FFFu + ((v >> 16) & 1u)) >> 16;
  h = (ushort_t)hb; l = (ushort_t)lb;
}

__global__ __launch_bounds__(256) void split_kernel(const float* __restrict__ src,
                                                    ushort_t* __restrict__ hi,
                                                    ushort_t* __restrict__ lo, int n) {
  int i = blockIdx.x * blockDim.x + threadIdx.x;
  int stride = gridDim.x * blockDim.x;
  for (; i < n; i += stride) {
    ushort_t h, l;
    split_bf16(src[i], h, l);
    hi[i] = h; lo[i] = l;
  }
}

// hi-only (round-to-nearest-even bf16) for weights: 2-term scheme needs only wh
__global__ __launch_bounds__(256) void split_hi_kernel(const float* __restrict__ src,
                                                       ushort_t* __restrict__ hi, int n) {
  int i = blockIdx.x * blockDim.x + threadIdx.x;
  int stride = gridDim.x * blockDim.x;
  for (; i < n; i += stride) {
    uint_t u = __float_as_uint(src[i]);
    hi[i] = (ushort_t)((u + 0x7FFFu + ((u >> 16) & 1u)) >> 16);
  }
}

__device__ __forceinline__ float sigmoidf_(float v) { return 1.0f / (1.0f + expf(-v)); }

// ---------------- hierarchical grid barrier (round-6 form, known good) ----------------
__device__ __forceinline__ void grid_barrier(unsigned* bar, int tid, int bid) {
  __syncthreads();
  if (tid == 0) {
    const int g = bid & 7;
    unsigned* arr    = bar + (g << 6);
    unsigned* rel    = bar + 1024 + (g << 6);
    unsigned* master = bar + 2048;
    unsigned gen = __hip_atomic_load(rel, __ATOMIC_RELAXED, __HIP_MEMORY_SCOPE_AGENT);
    unsigned a = __hip_atomic_fetch_add(arr, 1u, __ATOMIC_ACQ_REL, __HIP_MEMORY_SCOPE_AGENT);
    if (a == 31u) {
      __hip_atomic_store(arr, 0u, __ATOMIC_RELAXED, __HIP_MEMORY_SCOPE_AGENT);
      unsigned m = __hip_atomic_fetch_add(master, 1u, __ATOMIC_ACQ_REL, __HIP_MEMORY_SCOPE_AGENT);
      if (m == 7u) {
        __hip_atomic_store(master, 0u, __ATOMIC_RELAXED, __HIP_MEMORY_SCOPE_AGENT);
        #pragma unroll
        for (int i = 0; i < 8; ++i)
          __hip_atomic_fetch_add(bar + 1024 + (i << 6), 1u, __ATOMIC_ACQ_REL, __HIP_MEMORY_SCOPE_AGENT);
      }
    }
    while (__hip_atomic_load(rel, __ATOMIC_RELAXED, __HIP_MEMORY_SCOPE_AGENT) == gen)
      __builtin_amdgcn_s_sleep(1);
    (void)__hip_atomic_load(rel, __ATOMIC_ACQUIRE, __HIP_MEMORY_SCOPE_AGENT);
  }
  __syncthreads();
}

// ---------------- one GEMM phase (round-6 staging, 2-TERM: x = xh+xl exact, W = bf16 wh) ----------------
// acc = xh*wh + xl*wh  (W-lo stream eliminated: W bytes halve, MFMA 6->4 per gate)
template <int NG, int PH, int EPI>
__device__ __forceinline__ void phase_mm(
    char* smem, const int tid, const int bid, const int jb8, const bool active,
    const ushort_t* aAh, const ushort_t* aAl, int aApitch, int K1,
    const ushort_t* wAh,
    const ushort_t* aBh, const ushort_t* aBl, int aBpitch, int K2,
    const ushort_t* wBh,
    const float* bih, const float* bhh,
    const float* h_prev, float* h_out,
    ushort_t* out_hi, ushort_t* out_lo, int split_pitch,
    const float* bias, float* out_f32, int out_pitch)
{
  if (!active) return;
  constexpr int NSLOT = 4 + NG;          // A hi(2) + A lo(2) + W hi(NG)
  constexpr int BUFB  = NSLOT * 4096;    // staging buffer bytes
  constexpr int PGc = PH * NG;

  const int xcd = bid & 7;
  const int wi = bid >> 3;
  const int Mb = wi & 3;
  const int jb = xcd * jb8 + (wi >> 2);
  const int b0 = Mb * 32;
  const int j0 = jb * 16;

  const int NC1 = K1 >> 7;
  const int NC2 = (PH == 2) ? (K2 >> 7) : 0;
  const int NC = NC1 + NC2;

  const char* g[NSLOT];
  auto build = [&](const ushort_t* ah, const ushort_t* al, int apitch,
                   const ushort_t* wh, int K) {
    #pragma unroll
    for (int u = 0; u < NSLOT; ++u) {
      int slot = tid + 256 * u;
      int mat = (slot < 512) ? 0 : (slot < 1024) ? 1 : 2;
      int rr  = slot - ((mat == 0) ? 0 : (mat == 1) ? 512 : 1024);
      int row = rr >> 4, cp = rr & 15;
      int cc = cp ^ (row & 15);
      const ushort_t* base; size_t off;
      if (mat <= 1) { base = mat ? al : ah; off = (size_t)(b0 + row) * apitch + cc * 8; }
      else {
        int wrow = (NG == 3) ? ((row >> 4) * H + j0 + (row & 15)) : (j0 + row);
        base = wh; off = (size_t)wrow * K + cc * 8;
      }
      g[u] = (const char*)(base + off);
    }
  };

  // fragment read offsets
  const int s = tid >> 6;
  const int q = (tid >> 4) & 3;
  const int r = tid & 15;
  const int gs = (((4 * s + q) ^ r) << 4);
  const int offA00 = r * 256 + gs;
  const int offA01 = (16 + r) * 256 + gs;
  const int offA10 = 8192 + r * 256 + gs;
  const int offA11 = 8192 + (16 + r) * 256 + gs;
  int offW[NG];
  #pragma unroll
  for (int gg = 0; gg < NG; ++gg)
    offW[gg] = 16384 + (gg * 16 + r) * 256 + gs;

  f32x4 accA[NG][2];
  f32x4 accB[NG][2];
  #pragma unroll
  for (int gg = 0; gg < NG; ++gg)
    #pragma unroll
    for (int mf = 0; mf < 2; ++mf) {
      accA[gg][mf] = (f32x4){0.f, 0.f, 0.f, 0.f};
      accB[gg][mf] = (f32x4){0.f, 0.f, 0.f, 0.f};
    }

  const unsigned wofs = (unsigned)(tid >> 6) * 1024;
  auto issue = [&](int bsel, int koff) {
    #pragma unroll
    for (int u = 0; u < NSLOT; ++u) {
      __builtin_amdgcn_global_load_lds(
          (const __attribute__((address_space(1))) void*)(g[u] + koff),
          (__attribute__((address_space(3))) void*)(smem + bsel * BUFB + u * 4096 + wofs),
          16, 0, 0);
    }
  };

  auto compute = [&](int bsel, f32x4 (&acc)[NG][2]) {
    const char* base = smem + bsel * BUFB;
    bf16x8 ah0 = *(const bf16x8*)(base + offA00);
    bf16x8 ah1 = *(const bf16x8*)(base + offA01);
    bf16x8 al0 = *(const bf16x8*)(base + offA10);
    bf16x8 al1 = *(const bf16x8*)(base + offA11);
    #pragma unroll
    for (int gg = 0; gg < NG; ++gg) {
      bf16x8 wh = *(const bf16x8*)(base + offW[gg]);
      acc[gg][0] = __builtin_amdgcn_mfma_f32_16x16x32_bf16(ah0, wh, acc[gg][0], 0, 0, 0);
      acc[gg][0] = __builtin_amdgcn_mfma_f32_16x16x32_bf16(al0, wh, acc[gg][0], 0, 0, 0);
      acc[gg][1] = __builtin_amdgcn_mfma_f32_16x16x32_bf16(ah1, wh, acc[gg][1], 0, 0, 0);
      acc[gg][1] = __builtin_amdgcn_mfma_f32_16x16x32_bf16(al1, wh, acc[gg][1], 0, 0, 0);
    }
  };

  // prologue
  build(aAh, aAl, aApitch, wAh, K1);
  issue(0, 0);

  #pragma unroll 1
  for (int c = 0; c < NC; ++c) {
    __syncthreads();
    if (c + 1 < NC) {
      if (PH == 2 && c + 1 == NC1) {
        build(aBh, aBl, aBpitch, wBh, K2);
        issue((c + 1) & 1, 0);
      } else {
        int koff = ((c + 1 >= NC1 && PH == 2) ? (c + 1 - NC1) : (c + 1)) * 256;
        issue((c + 1) & 1, koff);
      }
    }
    if (PH == 1 || c < NC1) compute(c & 1, accA);
    else                    compute(c & 1, accB);
  }
  __syncthreads();

  // cross-wave reduce (alias smem)
  const int lane = tid & 63;
  #pragma unroll
  for (int gg = 0; gg < NG; ++gg)
    #pragma unroll
    for (int mf = 0; mf < 2; ++mf) {
      *(f32x4*)(smem + (((s * PGc + gg) * 2 + mf) * 64 + lane) * 16) = accA[gg][mf];
      if (PH == 2)
        *(f32x4*)(smem + (((s * PGc + NG + gg) * 2 + mf) * 64 + lane) * 16) = accB[gg][mf];
    }
  __syncthreads();

  for (int o = tid; o < 512; o += 256) {
    int bb = o >> 4, jj = o & 15;
    int mf = bb >> 4, br = bb & 15, qq = br >> 2, rg = br & 3;
    int ln = jj + qq * 16;
    float v[PGc];
    #pragma unroll
    for (int gp = 0; gp < PGc; ++gp) {
      float sum = 0.f;
      #pragma unroll
      for (int ss = 0; ss < 4; ++ss)
        sum += *(const float*)(smem + (((ss * PGc + gp) * 2 + mf) * 64 + ln) * 16 + rg * 4);
      v[gp] = sum;
    }
    int bglob = b0 + bb, jglob = j0 + jj;
    if (EPI == 0) {
      float ir = v[0] + bih[jglob];
      float iz = v[1] + bih[H + jglob];
      float in_ = v[2] + bih[2 * H + jglob];
      float hr = v[3] + bhh[jglob];
      float hz = v[4] + bhh[H + jglob];
      float hn = v[5] + bhh[2 * H + jglob];
      float rr_ = sigmoidf_(ir + hr);
      float zz_ = sigmoidf_(iz + hz);
      float nn_ = tanhf(in_ + rr_ * hn);
      float hp = h_prev[(size_t)bglob * H + jglob];
      float ho = (1.f - zz_) * nn_ + zz_ * hp;
      h_out[(size_t)bglob * H + jglob] = ho;
      ushort_t hb, lb;
      split_bf16(ho, hb, lb);
      out_hi[(size_t)bglob * H + jglob] = hb;
      out_lo[(size_t)bglob * H + jglob] = lb;
    } else if (EPI == 1) {
      float vv = v[0] + bias[jglob];
      vv = fmaxf(vv, 0.f);
      ushort_t hb, lb;
      split_bf16(vv, hb, lb);
      out_hi[(size_t)bglob * split_pitch + jglob] = hb;
      out_lo[(size_t)bglob * split_pitch + jglob] = lb;
    } else {
      float vv = v[0] + bias[jglob];
      out_f32[(size_t)bglob * out_pitch + jglob] = vv;
      ushort_t hb, lb;
      split_bf16(vv, hb, lb);
      out_hi[(size_t)bglob * split_pitch + jglob] = hb;
      out_lo[(size_t)bglob * split_pitch + jglob] = lb;
    }
  }
  __syncthreads();
}

// ---------------- persistent kernel ----------------

struct PParams {
  const ushort_t *ctxh, *ctxl;
  const ushort_t *wih0h, *whh0h;
  const ushort_t *wih1h, *whh1h;
  const ushort_t *w1h, *w2h;
  const float *bih0, *bhh0, *bih1, *bhh1, *bp1, *bp2;
  float *h0f0, *h0f1, *h1f0, *h1f1;
  ushort_t *h0hi0, *h0lo0, *h0hi1, *h0lo1;
  ushort_t *h1hi0, *h1lo0, *h1hi1, *h1lo1;
  ushort_t *h0Ahi, *h0Alo;      // all-t encoder h0 split [T_in][B][H]
  ushort_t *phi, *plo, *yhi, *ylo;
  float* out;
  unsigned* bar;
  int T_in, n_pred, ctx_pitch;
};

__global__ __launch_bounds__(256, 1) void gru_persistent(PParams P) {
  __shared__ char smem[81920];
  const int tid = threadIdx.x;
  const int bid = blockIdx.x;

  float* h0f[2] = {P.h0f0, P.h0f1};
  float* h1f[2] = {P.h1f0, P.h1f1};
  ushort_t* h0hi[2] = {P.h0hi0, P.h0hi1};
  ushort_t* h0lo[2] = {P.h0lo0, P.h0lo1};
  ushort_t* h1hi[2] = {P.h1hi0, P.h1hi1};
  ushort_t* h1lo[2] = {P.h1lo0, P.h1lo1};

  int p0 = 0, p1 = 0;

  // -------- encoder chain 1: layer-0 for all t --------
  const ushort_t* e0ph = h0hi[0];
  const ushort_t* e0pl = h0lo[0];
  #pragma unroll 1
  for (int t = 0; t < P.T_in; ++t) {
    const int n0 = p0 ^ 1;
    ushort_t* oh = P.h0Ahi + (size_t)t * B * H;
    ushort_t* ol = P.h0Alo + (size_t)t * B * H;
    phase_mm<3, 2, 0>(smem, tid, bid, 8, true,
        P.ctxh + (size_t)t * LATENT, P.ctxl + (size_t)t * LATENT, P.ctx_pitch, LATENT,
        P.wih0h,
        e0ph, e0pl, H, H, P.whh0h,
        P.bih0, P.bhh0, h0f[p0], h0f[n0], oh, ol, H,
        nullptr, nullptr, 0);
    grid_barrier(P.bar, tid, bid);
    e0ph = oh; e0pl = ol; p0 = n0;
  }

  // -------- encoder chain 2: layer-1 for all t --------
  #pragma unroll 1
  for (int t = 0; t < P.T_in; ++t) {
    const int n1 = p1 ^ 1;
    phase_mm<3, 2, 0>(smem, tid, bid, 8, true,
        P.h0Ahi + (size_t)t * B * H, P.h0Alo + (size_t)t * B * H, H, H,
        P.wih1h,
        h1hi[p1], h1lo[p1], H, H, P.whh1h,
        P.bih1, P.bhh1, h1f[p1], h1f[n1], h1hi[n1], h1lo[n1], H,
        nullptr, nullptr, 0);
    grid_barrier(P.bar, tid, bid);
    p1 = n1;
  }

  // -------- decoder --------
  const ushort_t* d0ph = e0ph;
  const ushort_t* d0pl = e0pl;
  #pragma unroll 1
  for (int t = 0; t < P.n_pred; ++t) {
    const ushort_t *xh, *xl; int xpitch;
    if (t == 0) {
      xh = P.ctxh + (size_t)(P.T_in - 1) * LATENT;
      xl = P.ctxl + (size_t)(P.T_in - 1) * LATENT;
      xpitch = P.ctx_pitch;
    } else {
      xh = P.yhi; xl = P.ylo; xpitch = LATENT;
    }
    const int n0 = p0 ^ 1;
    phase_mm<3, 2, 0>(smem, tid, bid, 8, true,
        xh, xl, xpitch, LATENT,
        P.wih0h,
        d0ph, d0pl, H, H, P.whh0h,
        P.bih0, P.bhh0, h0f[p0], h0f[n0], h0hi[n0], h0lo[n0], H,
        nullptr, nullptr, 0);
    grid_barrier(P.bar, tid, bid);
    d0ph = h0hi[n0]; d0pl = h0lo[n0];
    const int n1 = p1 ^ 1;
    phase_mm<3, 2, 0>(smem, tid, bid, 8, true,
        h0hi[n0], h0lo[n0], H, H,
        P.wih1h,
        h1hi[p1], h1lo[p1], H, H, P.whh1h,
        P.bih1, P.bhh1, h1f[p1], h1f[n1], h1hi[n1], h1lo[n1], H,
        nullptr, nullptr, 0);
    grid_barrier(P.bar, tid, bid);
    // p = relu(h1 @ w1^T + bp1)
    phase_mm<1, 1, 1>(smem, tid, bid, 8, true,
        h1hi[n1], h1lo[n1], H, H,
        P.w1h,
        nullptr, nullptr, 0, 0, nullptr,
        nullptr, nullptr, nullptr, nullptr, P.phi, P.plo, H,
        P.bp1, nullptr, 0);
    grid_barrier(P.bar, tid, bid);
    // y = p @ w2^T + bp2 -> out[:, t, :] + y split
    phase_mm<1, 1, 2>(smem, tid, bid, 4, bid < 128,
        P.phi, P.plo, H, H,
        P.w2h,
        nullptr, nullptr, 0, 0, nullptr,
        nullptr, nullptr, nullptr, nullptr, P.yhi, P.ylo, LATENT,
        P.bp2, P.out + (size_t)t * LATENT, P.n_pred * LATENT);
    grid_barrier(P.bar, tid, bid);
    p0 = n0; p1 = n1;
  }
}

// ---------------- fp32 fallback (round-1, known-good) ----------------

__global__ __launch_bounds__(256) void gru_cell_kernel(
    const float* __restrict__ x, int xs, int Kih,
    const float* __restrict__ h_prev,
    const float* __restrict__ wih, const float* __restrict__ whh,
    const float* __restrict__ bih, const float* __restrict__ bhh,
    float* __restrict__ h_out)
{
  __shared__ float Xs[32][33];
  __shared__ float Ws[48][33];
  const int tid = threadIdx.x;
  const int b0 = blockIdx.x * 32;
  const int j0 = blockIdx.y * 16;
  const int bg = tid & 15;
  const int jj = tid >> 4;
  const int j = j0 + jj;
  float accA[2][3];
  float accB[2][3];
  #pragma unroll
  for (int g = 0; g < 3; ++g) {
    const float bi = bih[g * H + j];
    const float bh = bhh[g * H + j];
    accA[0][g] = bi; accA[1][g] = bi;
    accB[0][g] = bh; accB[1][g] = bh;
  }
  for (int k0 = 0; k0 < Kih; k0 += 32) {
    {
      const int rr = tid >> 3, c4 = (tid & 7) << 2;
      const float4 v = *reinterpret_cast<const float4*>(&x[(size_t)(b0 + rr) * xs + k0 + c4]);
      Xs[rr][c4 + 0] = v.x; Xs[rr][c4 + 1] = v.y; Xs[rr][c4 + 2] = v.z; Xs[rr][c4 + 3] = v.w;
    }
    for (int li = tid; li < 48 * 8; li += 256) {
      const int rr = li >> 3, c4 = (li & 7) << 2;
      const int g = rr >> 4, jr = rr & 15;
      const float4 v = *reinterpret_cast<const float4*>(&wih[(size_t)(g * H + j0 + jr) * Kih + k0 + c4]);
      Ws[rr][c4 + 0] = v.x; Ws[rr][c4 + 1] = v.y; Ws[rr][c4 + 2] = v.z; Ws[rr][c4 + 3] = v.w;
    }
    __syncthreads();
    #pragma unroll
    for (int k = 0; k < 32; ++k) {
      const float x0 = Xs[bg][k];
      const float x1 = Xs[bg + 16][k];
      #pragma unroll
      for (int g = 0; g < 3; ++g) {
        const float wv = Ws[g * 16 + jj][k];
        accA[0][g] = fmaf(x0, wv, accA[0][g]);
        accA[1][g] = fmaf(x1, wv, accA[1][g]);
      }
    }
    __syncthreads();
  }
  for (int k0 = 0; k0 < H; k0 += 32) {
    {
      const int rr = tid >> 3, c4 = (tid & 7) << 2;
      const float4 v = *reinterpret_cast<const float4*>(&h_prev[(size_t)(b0 + rr) * H + k0 + c4]);
      Xs[rr][c4 + 0] = v.x; Xs[rr][c4 + 1] = v.y; Xs[rr][c4 + 2] = v.z; Xs[rr][c4 + 3] = v.w;
    }
    for (int li = tid; li < 48 * 8; li += 256) {
      const int rr = li >> 3, c4 = (li & 7) << 2;
      const int g = rr >> 4, jr = rr & 15;
      const float4 v = *reinterpret_cast<const float4*>(&whh[(size_t)(g * H + j0 + jr) * H + k0 + c4]);
      Ws[rr][c4 + 0] = v.x; Ws[rr][c4 + 1] = v.y; Ws[rr][c4 + 2] = v.z; Ws[rr][c4 + 3] = v.w;
    }
    __syncthreads();
    #pragma unroll
    for (int k = 0; k < 32; ++k) {
      const float h0v = Xs[bg][k];
      const float h1v = Xs[bg + 16][k];
      #pragma unroll
      for (int g = 0; g < 3; ++g) {
        const float wv = Ws[g * 16 + jj][k];
        accB[0][g] = fmaf(h0v, wv, accB[0][g]);
        accB[1][g] = fmaf(h1v, wv, accB[1][g]);
      }
    }
    __syncthreads();
  }
  #pragma unroll
  for (int i = 0; i < 2; ++i) {
    const int b = b0 + bg + i * 16;
    const float hp = h_prev[(size_t)b * H + j];
    const float r = sigmoidf_(accA[i][0] + accB[i][0]);
    const float z = sigmoidf_(accA[i][1] + accB[i][1]);
    const float n = tanhf(accA[i][2] + r * accB[i][2]);
    h_out[(size_t)b * H + j] = (1.0f - z) * n + z * hp;
  }
}

__global__ __launch_bounds__(256) void gemm_bias_kernel(
    const float* __restrict__ X, int xs, int K,
    const float* __restrict__ W, const float* __restrict__ bias,
    float* __restrict__ out1, int o1s,
    float* __restrict__ out2, int o2s,
    int relu)
{
  __shared__ float Xs[32][33];
  __shared__ float Ws[16][33];
  const int tid = threadIdx.x;
  const int b0 = blockIdx.x * 32;
  const int n0 = blockIdx.y * 16;
  const int bg = tid & 15;
  const int nn = tid >> 4;
  const int n = n0 + nn;
  float acc0 = bias[n];
  float acc1 = acc0;
  for (int k0 = 0; k0 < K; k0 += 32) {
    {
      const int rr = tid >> 3, c4 = (tid & 7) << 2;
      const float4 v = *reinterpret_cast<const float4*>(&X[(size_t)(b0 + rr) * xs + k0 + c4]);
      Xs[rr][c4 + 0] = v.x; Xs[rr][c4 + 1] = v.y; Xs[rr][c4 + 2] = v.z; Xs[rr][c4 + 3] = v.w;
    }
    if (tid < 128) {
      const int rr = tid >> 3, c4 = (tid & 7) << 2;
      const float4 v = *reinterpret_cast<const float4*>(&W[(size_t)(n0 + rr) * K + k0 + c4]);
      Ws[rr][c4 + 0] = v.x; Ws[rr][c4 + 1] = v.y; Ws[rr][c4 + 2] = v.z; Ws[rr][c4 + 3] = v.w;
    }
    __syncthreads();
    #pragma unroll
    for (int k = 0; k < 32; ++k) {
      const float wv = Ws[nn][k];
      acc0 = fmaf(Xs[bg][k], wv, acc0);
      acc1 = fmaf(Xs[bg + 16][k], wv, acc1);
    }
    __syncthreads();
  }
  if (relu) { acc0 = fmaxf(acc0, 0.0f); acc1 = fmaxf(acc1, 0.0f); }
  const int ba = b0 + bg, bb = b0 + bg + 16;
  out1[(size_t)ba * o1s + n] = acc0;
  out1[(size_t)bb * o1s + n] = acc1;
  if (out2 != nullptr) {
    out2[(size_t)ba * o2s + n] = acc0;
    out2[(size_t)bb * o2s + n] = acc1;
  }
}

// ---------------- host launch ----------------

extern "C" void kernel_launch(void* const* d_in, const int* in_sizes, int n_in,
                              void* d_out, int out_size, void* d_ws, size_t ws_size,
                              hipStream_t stream) {
  (void)n_in;
  const float* ctx  = (const float*)d_in[0];
  const float* wih0 = (const float*)d_in[1];
  const float* whh0 = (const float*)d_in[2];
  const float* bih0 = (const float*)d_in[3];
  const float* bhh0 = (const float*)d_in[4];
  const float* wih1 = (const float*)d_in[5];
  const float* whh1 = (const float*)d_in[6];
  const float* bih1 = (const float*)d_in[7];
  const float* bhh1 = (const float*)d_in[8];
  const float* w1   = (const float*)d_in[9];
  const float* bp1  = (const float*)d_in[10];
  const float* w2   = (const float*)d_in[11];
  const float* bp2  = (const float*)d_in[12];

  const int T_in   = in_sizes[0] / (B * LATENT);
  const int n_pred = out_size / (B * LATENT);
  float* out = (float*)d_out;

  // ---- ws layout for MFMA path ----
  size_t cur = 0;
  auto alloc = [&](size_t bytes) -> void* {
    void* p = (char*)d_ws + cur;
    cur += (bytes + 255) & ~(size_t)255;
    return p;
  };
  const int E_wih0 = 3 * H * LATENT, E_whh0 = 3 * H * H;
  const int E_wih1 = 3 * H * H, E_whh1 = 3 * H * H;
  const int E_w1 = H * H, E_w2 = LATENT * H;
  const int E_ctx = in_sizes[0];

  ushort_t* wih0h = (ushort_t*)alloc(E_wih0 * 2);
  ushort_t* whh0h = (ushort_t*)alloc(E_whh0 * 2);
  ushort_t* wih1h = (ushort_t*)alloc(E_wih1 * 2);
  ushort_t* whh1h = (ushort_t*)alloc(E_whh1 * 2);
  ushort_t* w1h   = (ushort_t*)alloc(E_w1 * 2);
  ushort_t* w2h   = (ushort_t*)alloc(E_w2 * 2);
  ushort_t* ctxh  = (ushort_t*)alloc((size_t)E_ctx * 2);
  ushort_t* ctxl  = (ushort_t*)alloc((size_t)E_ctx * 2);
  ushort_t* h0Ahi = (ushort_t*)alloc((size_t)T_in * B * H * 2);
  ushort_t* h0Alo = (ushort_t*)alloc((size_t)T_in * B * H * 2);
  size_t zero_start = cur;
  float* h0f[2]; float* h1f[2];
  ushort_t* h0hi[2]; ushort_t* h0lo[2]; ushort_t* h1hi[2]; ushort_t* h1lo[2];
  h0f[0] = (float*)alloc(B * H * 4); h0f[1] = (float*)alloc(B * H * 4);
  h1f[0] = (float*)alloc(B * H * 4); h1f[1] = (float*)alloc(B * H * 4);
  h0hi[0] = (ushort_t*)alloc(B * H * 2); h0lo[0] = (ushort_t*)alloc(B * H * 2);
  h0hi[1] = (ushort_t*)alloc(B * H * 2); h0lo[1] = (ushort_t*)alloc(B * H * 2);
  h1hi[0] = (ushort_t*)alloc(B * H * 2); h1lo[0] = (ushort_t*)alloc(B * H * 2);
  h1hi[1] = (ushort_t*)alloc(B * H * 2); h1lo[1] = (ushort_t*)alloc(B * H * 2);
  ushort_t* phi = (ushort_t*)alloc(B * H * 2); ushort_t* plo = (ushort_t*)alloc(B * H * 2);
  ushort_t* yhi = (ushort_t*)alloc(B * LATENT * 2); ushort_t* ylo = (ushort_t*)alloc(B * LATENT * 2);
  unsigned* bar = (unsigned*)alloc(16384);
  size_t zero_bytes = cur - zero_start;
  size_t required = cur;

  if (ws_size >= required) {
    // ---------- MFMA 2-term split-bf16 persistent path ----------
    auto splitA = [&](const float* s, ushort_t* hi, ushort_t* lo, int n) {
      int blocks = (n + 255) / 256; if (blocks > 2048) blocks = 2048;
      split_kernel<<<blocks, 256, 0, stream>>>(s, hi, lo, n);
    };
    auto splitW = [&](const float* s, ushort_t* hi, int n) {
      int blocks = (n + 255) / 256; if (blocks > 2048) blocks = 2048;
      split_hi_kernel<<<blocks, 256, 0, stream>>>(s, hi, n);
    };
    splitW(wih0, wih0h, E_wih0);
    splitW(whh0, whh0h, E_whh0);
    splitW(wih1, wih1h, E_wih1);
    splitW(whh1, whh1h, E_whh1);
    splitW(w1, w1h, E_w1);
    splitW(w2, w2h, E_w2);
    splitA(ctx, ctxh, ctxl, E_ctx);
    {
      int n4 = (int)(zero_bytes / 16);
      zero4_kernel<<<2048, 256, 0, stream>>>((float4*)((char*)d_ws + zero_start), n4);
    }

    PParams P;
    P.ctxh = ctxh; P.ctxl = ctxl;
    P.wih0h = wih0h; P.whh0h = whh0h;
    P.wih1h = wih1h; P.whh1h = whh1h;
    P.w1h = w1h; P.w2h = w2h;
    P.bih0 = bih0; P.bhh0 = bhh0; P.bih1 = bih1; P.bhh1 = bhh1;
    P.bp1 = bp1; P.bp2 = bp2;
    P.h0f0 = h0f[0]; P.h0f1 = h0f[1]; P.h1f0 = h1f[0]; P.h1f1 = h1f[1];
    P.h0hi0 = h0hi[0]; P.h0lo0 = h0lo[0]; P.h0hi1 = h0hi[1]; P.h0lo1 = h0lo[1];
    P.h1hi0 = h1hi[0]; P.h1lo0 = h1lo[0]; P.h1hi1 = h1hi[1]; P.h1lo1 = h1lo[1];
    P.h0Ahi = h0Ahi; P.h0Alo = h0Alo;
    P.phi = phi; P.plo = plo; P.yhi = yhi; P.ylo = ylo;
    P.out = out; P.bar = bar;
    P.T_in = T_in; P.n_pred = n_pred; P.ctx_pitch = T_in * LATENT;

    gru_persistent<<<256, 256, 0, stream>>>(P);
    return;
  }

  // ---------- fp32 fallback path (round-1) ----------
  float* ws = (float*)d_ws;
  float* h0a = ws;
  float* h0b = h0a + (size_t)B * H;
  float* h1a = h0b + (size_t)B * H;
  float* h1b = h1a + (size_t)B * H;
  float* p   = h1b + (size_t)B * H;
  {
    int n4 = (4 * B * H) / 4;
    zero4_kernel<<<256, 256, 0, stream>>>((float4*)h0a, n4);
  }
  float* y = p + (size_t)B * H;
  float* h0p = h0a; float* h0n = h0b;
  float* h1p = h1a; float* h1n = h1b;
  const dim3 cgrid(4, 64);
  for (int t = 0; t < T_in; ++t) {
    const float* x = ctx + (size_t)t * LATENT;
    gru_cell_kernel<<<cgrid, 256, 0, stream>>>(x, T_in * LATENT, LATENT,
                                               h0p, wih0, whh0, bih0, bhh0, h0n);
    gru_cell_kernel<<<cgrid, 256, 0, stream>>>(h0n, H, H,
                                               h1p, wih1, whh1, bih1, bhh1, h1n);
    float* tmp;
    tmp = h0p; h0p = h0n; h0n = tmp;
    tmp = h1p; h1p = h1n; h1n = tmp;
  }
  for (int t = 0; t < n_pred; ++t) {
    const float* x; int xstride;
    if (t == 0) { x = ctx + (size_t)(T_in - 1) * LATENT; xstride = T_in * LATENT; }
    else        { x = y; xstride = LATENT; }
    gru_cell_kernel<<<cgrid, 256, 0, stream>>>(x, xstride, LATENT,
                                               h0p, wih0, whh0, bih0, bhh0, h0n);
    gru_cell_kernel<<<cgrid, 256, 0, stream>>>(h0n, H, H,
                                               h1p, wih1, whh1, bih1, bhh1, h1n);
    gemm_bias_kernel<<<dim3(4, H / 16), 256, 0, stream>>>(h1n, H, H, w1, bp1,
                                                          p, H, nullptr, 0, 1);
    gemm_bias_kernel<<<dim3(4, LATENT / 16), 256, 0, stream>>>(p, H, H, w2, bp2,
                                                               y, LATENT,
                                                               out + (size_t)t * LATENT,
                                                               n_pred * LATENT, 0);
    float* tmp;
    tmp = h0p; h0p = h0n; h0n = tmp;
    tmp = h1p; h1p = h1n; h1n = tmp;
  }
}